// Round 1
// baseline (1890.268 us; speedup 1.0000x reference)
//
#include <hip/hip_runtime.h>
#include <stdint.h>

typedef unsigned short u16;
typedef __bf16 bf16x8 __attribute__((ext_vector_type(8)));
typedef float f32x4 __attribute__((ext_vector_type(4)));

// round-to-nearest-even f32 -> bf16
__device__ __forceinline__ u16 f2bf(float f) {
  uint32_t u = __float_as_uint(f);
  u += 0x7FFFu + ((u >> 16) & 1u);
  return (u16)(u >> 16);
}

// ---------------------------------------------------------------------------
// zero the two scale accumulators (ws is poisoned 0xAA before every launch)
__global__ void zero_kernel(float* sums) {
  if (threadIdx.x < 2) sums[threadIdx.x] = 0.f;
}

// ---------------------------------------------------------------------------
// LayerNorm over concat[x_re row, x_im row] (8192 elems), write bf16 A[8192][8192]
__global__ __launch_bounds__(256) void ln_kernel(
    const float* __restrict__ xr, const float* __restrict__ xi,
    const float* __restrict__ gamma, const float* __restrict__ beta,
    u16* __restrict__ A)
{
  const int m = blockIdx.x;
  const int t = threadIdx.x;
  const float4* xr4 = (const float4*)(xr + (size_t)m * 4096);
  const float4* xi4 = (const float4*)(xi + (size_t)m * 4096);
  float4 vr[4], vi[4];
  float s = 0.f, ss = 0.f;
#pragma unroll
  for (int j = 0; j < 4; ++j) {
    vr[j] = xr4[t + j * 256];
    vi[j] = xi4[t + j * 256];
    s  += vr[j].x + vr[j].y + vr[j].z + vr[j].w;
    s  += vi[j].x + vi[j].y + vi[j].z + vi[j].w;
    ss += vr[j].x * vr[j].x + vr[j].y * vr[j].y + vr[j].z * vr[j].z + vr[j].w * vr[j].w;
    ss += vi[j].x * vi[j].x + vi[j].y * vi[j].y + vi[j].z * vi[j].z + vi[j].w * vi[j].w;
  }
#pragma unroll
  for (int o = 32; o > 0; o >>= 1) {
    s  += __shfl_xor(s, o);
    ss += __shfl_xor(ss, o);
  }
  __shared__ float red[10];
  if ((t & 63) == 0) { red[t >> 6] = s; red[4 + (t >> 6)] = ss; }
  __syncthreads();
  if (t == 0) {
    float S  = red[0] + red[1] + red[2] + red[3];
    float SS = red[4] + red[5] + red[6] + red[7];
    float mu = S * (1.f / 8192.f);
    float var = SS * (1.f / 8192.f) - mu * mu;
    red[8] = mu;
    red[9] = rsqrtf(var + 1e-6f);
  }
  __syncthreads();
  const float mu = red[8], rstd = red[9];
  u16* Arow = A + (size_t)m * 8192;
#pragma unroll
  for (int j = 0; j < 4; ++j) {
    int k0 = (t + j * 256) * 4;
    float4 g = *(const float4*)(gamma + k0);
    float4 b = *(const float4*)(beta + k0);
    ushort4 o4;
    o4.x = f2bf((vr[j].x - mu) * rstd * g.x + b.x);
    o4.y = f2bf((vr[j].y - mu) * rstd * g.y + b.y);
    o4.z = f2bf((vr[j].z - mu) * rstd * g.z + b.z);
    o4.w = f2bf((vr[j].w - mu) * rstd * g.w + b.w);
    *(ushort4*)(Arow + k0) = o4;
  }
#pragma unroll
  for (int j = 0; j < 4; ++j) {
    int k0 = 4096 + (t + j * 256) * 4;
    float4 g = *(const float4*)(gamma + k0);
    float4 b = *(const float4*)(beta + k0);
    ushort4 o4;
    o4.x = f2bf((vi[j].x - mu) * rstd * g.x + b.x);
    o4.y = f2bf((vi[j].y - mu) * rstd * g.y + b.y);
    o4.z = f2bf((vi[j].z - mu) * rstd * g.z + b.z);
    o4.w = f2bf((vi[j].w - mu) * rstd * g.w + b.w);
    *(ushort4*)(Arow + k0) = o4;
  }
}

// ---------------------------------------------------------------------------
// Phase-quantize weights into ternary bf16 B[8192][8192]:
//   row o        : [ q_re[o,:] | -q_im[o,:] ]   (y_re)
//   row o + 4096 : [ q_im[o,:] |  q_re[o,:] ]   (y_im)
// also accumulate sum|w_re|, sum|w_im| into sums[0..1]
__global__ __launch_bounds__(256) void quant_kernel(
    const float* __restrict__ wre, const float* __restrict__ wim,
    u16* __restrict__ Bq, float* __restrict__ sums)
{
  const int o = blockIdx.x;
  const int t = threadIdx.x;
  const float4* r4 = (const float4*)(wre + (size_t)o * 4096);
  const float4* i4 = (const float4*)(wim + (size_t)o * 4096);
  float sre = 0.f, sim = 0.f;
  u16* row0 = Bq + (size_t)o * 8192;
  u16* row1 = Bq + (size_t)(o + 4096) * 8192;
#pragma unroll
  for (int j = 0; j < 4; ++j) {
    int fi = t + j * 256;  // float4 index within the row
    float4 a = r4[fi];
    float4 b = i4[fi];
    ushort4 qre, qim, nqim;
#define DOQ(c, fld) { \
      float ar = fabsf(a.fld), ai = fabsf(b.fld); \
      sre += ar; sim += ai; \
      float qr = (ar >= ai) ? ((a.fld > 0.f) ? 1.f : ((a.fld < 0.f) ? -1.f : 0.f)) : 0.f; \
      float qi = (ar >= ai) ? 0.f : ((b.fld > 0.f) ? 1.f : ((b.fld < 0.f) ? -1.f : 0.f)); \
      qre.c = f2bf(qr); qim.c = f2bf(qi); nqim.c = f2bf(-qi); }
    DOQ(x, x) DOQ(y, y) DOQ(z, z) DOQ(w, w)
#undef DOQ
    int k0 = fi * 4;
    *(ushort4*)(row0 + k0)        = qre;
    *(ushort4*)(row0 + 4096 + k0) = nqim;
    *(ushort4*)(row1 + k0)        = qim;
    *(ushort4*)(row1 + 4096 + k0) = qre;
  }
#pragma unroll
  for (int off = 32; off > 0; off >>= 1) {
    sre += __shfl_xor(sre, off);
    sim += __shfl_xor(sim, off);
  }
  __shared__ float red[8];
  if ((t & 63) == 0) { red[t >> 6] = sre; red[4 + (t >> 6)] = sim; }
  __syncthreads();
  if (t == 0) {
    atomicAdd(&sums[0], red[0] + red[1] + red[2] + red[3]);
    atomicAdd(&sums[1], red[4] + red[5] + red[6] + red[7]);
  }
}

// ---------------------------------------------------------------------------
// C[m,o] = sum_k A[m,k]*B[o,k], M=N=K=8192, bf16 MFMA 16x16x32.
// 128x128 tile, BK=64, 4 waves (2x2), global_load_lds(16B) with linear LDS dest
// and inverse-XOR-swizzled global source; XOR-swizzled ds_read_b128 (conflict-free).
// Epilogue scales by s_re / s_im and writes fp32 into the two output halves.
__global__ __launch_bounds__(256) void gemm_kernel(
    const u16* __restrict__ A, const u16* __restrict__ B,
    const float* __restrict__ sums, float* __restrict__ out)
{
  constexpr int K = 8192;
  __shared__ u16 ldsA[8192];  // 128 rows x 64 k (bf16), rows = 128 B
  __shared__ u16 ldsB[8192];

  const int bid = blockIdx.x;
  // XCD-aware swizzle: 4096 blocks, 8 XCDs, 512 contiguous per XCD
  const int swz = (bid & 7) * 512 + (bid >> 3);
  const int bm0 = (swz >> 6) << 7;  // 64 N-tiles per M-row
  const int bn0 = (swz & 63) << 7;

  const int t = threadIdx.x;
  const int lane = t & 63;
  const int wid = t >> 6;
  const int wr = wid >> 1, wc = wid & 1;

  // staging: per wave 4 calls of 1 KB each per matrix; LDS dest linear,
  // global source pre-permuted with the same XOR involution the reads use
  const u16* srcA[4];
  const u16* srcB[4];
  int ldsOff[4];
#pragma unroll
  for (int j = 0; j < 4; ++j) {
    int L = (wid * 4 + j) * 1024 + lane * 16;  // linear byte pos in tile
    int row = L >> 7;                          // 128-B rows
    int slot = (L >> 4) & 7;                   // 16-B slot within row
    int ksw = slot ^ (row & 7);                // involution
    srcA[j] = A + ((size_t)(bm0 + row) * K + ksw * 8);
    srcB[j] = B + ((size_t)(bn0 + row) * K + ksw * 8);
    ldsOff[j] = (wid * 4 + j) * 512;           // ushort units (uniform)
  }

  // fragment read offsets (fixed across kt): lane reads row (l&15), k-group (l>>4)
  int aOff[2][4], bOff[2][4];
#pragma unroll
  for (int kk = 0; kk < 2; ++kk)
#pragma unroll
    for (int f = 0; f < 4; ++f) {
      int rowA = wr * 64 + f * 16 + (lane & 15);
      int sA = ((kk * 4) + (lane >> 4)) ^ (rowA & 7);
      aOff[kk][f] = rowA * 64 + sA * 8;
      int rowB = wc * 64 + f * 16 + (lane & 15);
      int sB = ((kk * 4) + (lane >> 4)) ^ (rowB & 7);
      bOff[kk][f] = rowB * 64 + sB * 8;
    }

  f32x4 acc[4][4];
#pragma unroll
  for (int m = 0; m < 4; ++m)
#pragma unroll
    for (int n = 0; n < 4; ++n)
      acc[m][n] = (f32x4){0.f, 0.f, 0.f, 0.f};

  for (int kt = 0; kt < 128; ++kt) {
    __syncthreads();
#pragma unroll
    for (int j = 0; j < 4; ++j) {
      __builtin_amdgcn_global_load_lds(
          (const __attribute__((address_space(1))) void*)(srcA[j]),
          (__attribute__((address_space(3))) void*)(ldsA + ldsOff[j]), 16, 0, 0);
      srcA[j] += 64;
    }
#pragma unroll
    for (int j = 0; j < 4; ++j) {
      __builtin_amdgcn_global_load_lds(
          (const __attribute__((address_space(1))) void*)(srcB[j]),
          (__attribute__((address_space(3))) void*)(ldsB + ldsOff[j]), 16, 0, 0);
      srcB[j] += 64;
    }
    __syncthreads();
#pragma unroll
    for (int kk = 0; kk < 2; ++kk) {
      bf16x8 aF[4], bF[4];
#pragma unroll
      for (int f = 0; f < 4; ++f) aF[f] = *(const bf16x8*)(ldsA + aOff[kk][f]);
#pragma unroll
      for (int f = 0; f < 4; ++f) bF[f] = *(const bf16x8*)(ldsB + bOff[kk][f]);
#pragma unroll
      for (int m = 0; m < 4; ++m)
#pragma unroll
        for (int n = 0; n < 4; ++n)
          acc[m][n] = __builtin_amdgcn_mfma_f32_16x16x32_bf16(aF[m], bF[n], acc[m][n], 0, 0, 0);
    }
  }

  // epilogue: scale + split into (y_re, y_im) halves of d_out
  const int isIm = (bn0 >= 4096) ? 1 : 0;
  const float sc = sums[isIm] * (1.0f / 16777216.0f);  // mean|w|
  float* outp = out + (isIm ? (size_t)33554432 : (size_t)0);
  const int cb = (isIm ? bn0 - 4096 : bn0) + wc * 64 + (lane & 15);
  const int rb = bm0 + wr * 64 + ((lane >> 4) << 2);
#pragma unroll
  for (int m = 0; m < 4; ++m)
#pragma unroll
    for (int n = 0; n < 4; ++n) {
      int c = cb + n * 16;
      int r0 = rb + m * 16;
#pragma unroll
      for (int i = 0; i < 4; ++i)
        outp[(size_t)(r0 + i) * 4096 + c] = acc[m][n][i] * sc;
    }
}

// ---------------------------------------------------------------------------
extern "C" void kernel_launch(void* const* d_in, const int* in_sizes, int n_in,
                              void* d_out, int out_size, void* d_ws, size_t ws_size,
                              hipStream_t stream)
{
  const float* xr    = (const float*)d_in[0];
  const float* xi    = (const float*)d_in[1];
  const float* wre   = (const float*)d_in[2];
  const float* wim   = (const float*)d_in[3];
  const float* gamma = (const float*)d_in[4];
  const float* beta  = (const float*)d_in[5];
  float* out = (float*)d_out;

  // ws layout: [0,4096) scale sums; A bf16 8192x8192 (134 MB); B bf16 8192x8192 (134 MB)
  float* sums = (float*)d_ws;
  u16* A  = (u16*)((char*)d_ws + 4096);
  u16* Bq = (u16*)((char*)d_ws + 4096 + (size_t)134217728);

  hipLaunchKernelGGL(zero_kernel, dim3(1), dim3(64), 0, stream, sums);
  hipLaunchKernelGGL(quant_kernel, dim3(4096), dim3(256), 0, stream, wre, wim, Bq, sums);
  hipLaunchKernelGGL(ln_kernel, dim3(8192), dim3(256), 0, stream, xr, xi, gamma, beta, A);
  hipLaunchKernelGGL(gemm_kernel, dim3(4096), dim3(256), 0, stream, A, Bq, sums, out);
}